// Round 1
// baseline (517.233 us; speedup 1.0000x reference)
//
#include <hip/hip_runtime.h>
#include <hip/hip_bf16.h>
#include <stdint.h>

// Problem constants
#define BB 8
#define SS 1024
#define HH 16
#define DHD 64
#define DD 1024

typedef __attribute__((ext_vector_type(8))) short bf16x8;
typedef __attribute__((ext_vector_type(4))) float f32x4;

__device__ __forceinline__ unsigned short f2bf(float f) {
  unsigned u = __builtin_bit_cast(unsigned, f);
  u += 0x7fffu + ((u >> 16) & 1u);   // round-to-nearest-even
  return (unsigned short)(u >> 16);
}

// XOR swizzle for 128B-row LDS tiles: xor byte bits[6:4] with row bits[2:0].
__device__ __forceinline__ unsigned swz(unsigned a) { return a ^ ((a >> 3) & 0x70u); }

#define GLOAD16(gp, lp)                                                        \
  __builtin_amdgcn_global_load_lds(                                            \
      (const __attribute__((address_space(1))) unsigned int*)(gp),             \
      (__attribute__((address_space(3))) unsigned int*)(lp), 16, 0, 0)

#define MFMA16(a, b, c) __builtin_amdgcn_mfma_f32_16x16x32_bf16(a, b, c, 0, 0, 0)

// ---------------------------------------------------------------- K1: x -> bf16
__global__ __launch_bounds__(256) void cvt_x_kernel(const float* __restrict__ x,
                                                    unsigned short* __restrict__ xb) {
  int i = blockIdx.x * 256 + threadIdx.x;   // 8192 blocks * 256 = 2,097,152 float4s
  float4 v = ((const float4*)x)[i];
  ushort4 o;
  o.x = f2bf(v.x); o.y = f2bf(v.y); o.z = f2bf(v.z); o.w = f2bf(v.w);
  ((ushort4*)xb)[i] = o;
}

// ------------------------------------------- K1b: transpose weights -> bf16 [n][k]
__global__ __launch_bounds__(256) void transpose_w_kernel(
    const float* __restrict__ w0, const float* __restrict__ w1,
    const float* __restrict__ w2, const float* __restrict__ w3,
    unsigned short* __restrict__ o0, unsigned short* __restrict__ o1,
    unsigned short* __restrict__ o2, unsigned short* __restrict__ o3) {
  __shared__ float tile[32][33];
  const float* src; unsigned short* dst;
  if (blockIdx.z == 0)      { src = w0; dst = o0; }
  else if (blockIdx.z == 1) { src = w1; dst = o1; }
  else if (blockIdx.z == 2) { src = w2; dst = o2; }
  else                      { src = w3; dst = o3; }
  int n0 = blockIdx.x * 32, k0 = blockIdx.y * 32;
  int tx = threadIdx.x, ty = threadIdx.y;   // block (32,8)
#pragma unroll
  for (int j = 0; j < 32; j += 8)
    tile[ty + j][tx] = src[(size_t)(k0 + ty + j) * DD + n0 + tx];
  __syncthreads();
#pragma unroll
  for (int j = 0; j < 32; j += 8)
    dst[(size_t)(n0 + ty + j) * DD + k0 + tx] = f2bf(tile[tx][ty + j]);
}

// ------------------------------------------------- K2: projections GEMM (q,k,v)
// M=8192 (B*S), K=1024, N=3072 (wq|wk|wv). 128x128 tile, BK=64, 4 waves.
__global__ __launch_bounds__(256) void proj_gemm_kernel(
    const unsigned short* __restrict__ xb,
    const unsigned short* __restrict__ wqt, const unsigned short* __restrict__ wkt,
    const unsigned short* __restrict__ wvt,
    const float* __restrict__ bq, const float* __restrict__ bk, const float* __restrict__ bv,
    float* __restrict__ qo, float* __restrict__ ko, float* __restrict__ vo,
    unsigned short* __restrict__ qb, unsigned short* __restrict__ kbf,
    unsigned short* __restrict__ vt) {
  __shared__ __align__(128) unsigned short As[128 * 64];
  __shared__ __align__(128) unsigned short Bs[128 * 64];
  const int tid = threadIdx.x, lane = tid & 63, w = tid >> 6;
  const int wr = (w >> 1) * 64, wc = (w & 1) * 64;
  const int m0 = blockIdx.x * 128;
  const int mat = blockIdx.y >> 3;
  const int n0 = (blockIdx.y & 7) * 128;
  const unsigned short* Bg = (mat == 0) ? wqt : (mat == 1) ? wkt : wvt;
  const float* bias = (mat == 0) ? bq : (mat == 1) ? bk : bv;

  f32x4 acc[4][4];
  f32x4 z4 = {0.f, 0.f, 0.f, 0.f};
#pragma unroll
  for (int i = 0; i < 4; ++i)
#pragma unroll
    for (int j = 0; j < 4; ++j) acc[i][j] = z4;

  for (int kt = 0; kt < 1024; kt += 64) {
    __syncthreads();
#pragma unroll
    for (int i = 0; i < 4; ++i) {
      unsigned obase = (unsigned)(w * 4096 + i * 1024);
      unsigned a = swz(obase + (unsigned)lane * 16);
      GLOAD16((const char*)xb + ((size_t)(m0 + (int)(a >> 7)) * 1024 + kt) * 2 + (a & 127),
              (char*)As + obase);
      GLOAD16((const char*)Bg + ((size_t)(n0 + (int)(a >> 7)) * 1024 + kt) * 2 + (a & 127),
              (char*)Bs + obase);
    }
    __syncthreads();
#pragma unroll
    for (int ks = 0; ks < 2; ++ks) {
      bf16x8 af[4], bfr[4];
#pragma unroll
      for (int mi = 0; mi < 4; ++mi) {
        unsigned a = (unsigned)((wr + mi * 16 + (lane & 15)) * 128 + ks * 64 + ((lane >> 4) * 16));
        af[mi] = *(const bf16x8*)((const char*)As + swz(a));
      }
#pragma unroll
      for (int ni = 0; ni < 4; ++ni) {
        unsigned a = (unsigned)((wc + ni * 16 + (lane & 15)) * 128 + ks * 64 + ((lane >> 4) * 16));
        bfr[ni] = *(const bf16x8*)((const char*)Bs + swz(a));
      }
#pragma unroll
      for (int mi = 0; mi < 4; ++mi)
#pragma unroll
        for (int ni = 0; ni < 4; ++ni)
          acc[mi][ni] = MFMA16(af[mi], bfr[ni], acc[mi][ni]);
    }
  }

  float* fo = (mat == 0) ? qo : (mat == 1) ? ko : vo;
#pragma unroll
  for (int mi = 0; mi < 4; ++mi)
#pragma unroll
    for (int ni = 0; ni < 4; ++ni) {
      int col = n0 + wc + ni * 16 + (lane & 15);   // 0..1023 within this matrix
      float bs = bias[col];
#pragma unroll
      for (int r = 0; r < 4; ++r) {
        int row = m0 + wr + mi * 16 + ((lane >> 4) << 2) + r;  // 0..8191
        float v = acc[mi][ni][r] + bs;
        int b = row >> 10, s = row & 1023, h = col >> 6, dh = col & 63;
        size_t bh = (size_t)(b * HH + h);
        fo[(bh * SS + s) * DHD + dh] = v;                       // fp32 head-split out
        if (mat == 2) vt[(bh * DHD + dh) * SS + s] = f2bf(v);   // V transposed [bh][d][s]
        else ((mat == 0) ? qb : kbf)[(bh * SS + s) * DHD + dh] = f2bf(v);
      }
    }
}

// ------------------------------- K3: fused attention (qk, softmax, attn, PV -> z)
// Block = (b, h, 64-row q tile); 4 waves x 16 rows. Two passes over K/V chunks of 64.
__global__ __launch_bounds__(256) void attn_kernel(
    const unsigned short* __restrict__ qb, const unsigned short* __restrict__ kb,
    const unsigned short* __restrict__ vt, const float* __restrict__ mask,
    float* __restrict__ qk_out, float* __restrict__ attn_out,
    unsigned short* __restrict__ zb) {
  __shared__ __align__(128) unsigned short kbuf[64 * 64];
  __shared__ __align__(128) unsigned short vbuf[64 * 64];
  __shared__ __align__(128) unsigned short pbuf[4][16 * 64];
  __shared__ __align__(16) float mbuf[SS];

  const int tid = threadIdx.x, lane = tid & 63, w = tid >> 6;
  const int qt = blockIdx.x, h = blockIdx.y, b = blockIdx.z;
  const int bh = b * HH + h;
  const int r0 = qt * 64 + w * 16;

  ((float4*)mbuf)[tid] = ((const float4*)(mask + (size_t)b * SS))[tid];

  // Q fragments for this wave's 16 rows (held in registers both passes)
  bf16x8 aq[2];
  {
    const unsigned short* p = qb + (size_t)bh * SS * DHD + (size_t)(r0 + (lane & 15)) * DHD + ((lane >> 4) * 8);
    aq[0] = *(const bf16x8*)p;
    aq[1] = *(const bf16x8*)(p + 32);
  }
  float mq[4];
#pragma unroll
  for (int r = 0; r < 4; ++r)
    mq[r] = mask[(size_t)b * SS + r0 + ((lane >> 4) << 2) + r];

  const unsigned short* kbase = kb + (size_t)bh * SS * DHD;
  const char* vbase = (const char*)(vt + (size_t)bh * DHD * SS);
  float* qkb = qk_out + (size_t)bh * SS * SS;
  float* atb = attn_out + (size_t)bh * SS * SS;

  float m_run[4], l_run[4];
#pragma unroll
  for (int r = 0; r < 4; ++r) { m_run[r] = -INFINITY; l_run[r] = 0.f; }

  // ---------------- pass 1: logits -> qk_values, online (m,l)
  for (int kt = 0; kt < 16; ++kt) {
    int k0 = kt * 64;
    __syncthreads();
#pragma unroll
    for (int i = 0; i < 2; ++i) {
      unsigned obase = (unsigned)(w * 2048 + i * 1024);
      unsigned a = swz(obase + (unsigned)lane * 16);
      GLOAD16((const char*)(kbase + (size_t)k0 * 64) + a, (char*)kbuf + obase);
    }
    __syncthreads();
    float sm[4][4];
#pragma unroll
    for (int ct = 0; ct < 4; ++ct) {
      f32x4 acc = {0.f, 0.f, 0.f, 0.f};
#pragma unroll
      for (int ks = 0; ks < 2; ++ks) {
        unsigned a = (unsigned)((ct * 16 + (lane & 15)) * 128 + ks * 64 + ((lane >> 4) * 16));
        bf16x8 bk = *(const bf16x8*)((const char*)kbuf + swz(a));
        acc = MFMA16(aq[ks], bk, acc);
      }
      int col = k0 + ct * 16 + (lane & 15);
      float mk = mbuf[col];
      float* qrow = qkb + (size_t)(r0 + ((lane >> 4) << 2)) * SS + col;
#pragma unroll
      for (int r = 0; r < 4; ++r) {
        float logit = acc[r] * 0.125f;
        qrow[(size_t)r * SS] = logit;                       // unmasked logits
        float t = fminf(mq[r] + mk, 1.f);
        sm[ct][r] = logit + t * (-1.0e9f);
      }
    }
#pragma unroll
    for (int r = 0; r < 4; ++r) {
      float mx = fmaxf(fmaxf(sm[0][r], sm[1][r]), fmaxf(sm[2][r], sm[3][r]));
#pragma unroll
      for (int d = 1; d < 16; d <<= 1) mx = fmaxf(mx, __shfl_xor(mx, d, 64));
      float m_new = fmaxf(m_run[r], mx);
      float es = __expf(sm[0][r] - m_new) + __expf(sm[1][r] - m_new) +
                 __expf(sm[2][r] - m_new) + __expf(sm[3][r] - m_new);
#pragma unroll
      for (int d = 1; d < 16; d <<= 1) es += __shfl_xor(es, d, 64);
      l_run[r] = l_run[r] * __expf(m_run[r] - m_new) + es;
      m_run[r] = m_new;
    }
  }

  float inv_l[4];
#pragma unroll
  for (int r = 0; r < 4; ++r) inv_l[r] = 1.0f / l_run[r];

  // ---------------- pass 2: recompute logits, write attn, PV accumulate
  f32x4 zacc[4];
#pragma unroll
  for (int dt = 0; dt < 4; ++dt) zacc[dt] = (f32x4){0.f, 0.f, 0.f, 0.f};

  for (int kt = 0; kt < 16; ++kt) {
    int k0 = kt * 64;
    __syncthreads();
#pragma unroll
    for (int i = 0; i < 2; ++i) {
      unsigned obase = (unsigned)(w * 2048 + i * 1024);
      unsigned a = swz(obase + (unsigned)lane * 16);
      GLOAD16((const char*)(kbase + (size_t)k0 * 64) + a, (char*)kbuf + obase);
      GLOAD16(vbase + (size_t)(a >> 7) * (SS * 2) + (size_t)k0 * 2 + (a & 127),
              (char*)vbuf + obase);
    }
    __syncthreads();
#pragma unroll
    for (int ct = 0; ct < 4; ++ct) {
      f32x4 acc = {0.f, 0.f, 0.f, 0.f};
#pragma unroll
      for (int ks = 0; ks < 2; ++ks) {
        unsigned a = (unsigned)((ct * 16 + (lane & 15)) * 128 + ks * 64 + ((lane >> 4) * 16));
        bf16x8 bk = *(const bf16x8*)((const char*)kbuf + swz(a));
        acc = MFMA16(aq[ks], bk, acc);
      }
      int col = k0 + ct * 16 + (lane & 15);
      float mk = mbuf[col];
#pragma unroll
      for (int r = 0; r < 4; ++r) {
        float logit = acc[r] * 0.125f;
        float t = fminf(mq[r] + mk, 1.f);
        float e = __expf(logit + t * (-1.0e9f) - m_run[r]);
        float pn = e * inv_l[r];
        atb[(size_t)(r0 + ((lane >> 4) << 2) + r) * SS + col] = pn;
        unsigned a2 = (unsigned)((((lane >> 4) << 2) + r) * 128 + (ct * 16 + (lane & 15)) * 2);
        *(unsigned short*)((char*)pbuf[w] + swz(a2)) = f2bf(pn);
      }
    }
    // PV: z += P @ V  (P from this wave's pbuf, V from vbuf)
#pragma unroll
    for (int dt = 0; dt < 4; ++dt) {
#pragma unroll
      for (int ks = 0; ks < 2; ++ks) {
        unsigned ap = (unsigned)((lane & 15) * 128 + ks * 64 + ((lane >> 4) * 16));
        bf16x8 pa = *(const bf16x8*)((const char*)pbuf[w] + swz(ap));
        unsigned av = (unsigned)((dt * 16 + (lane & 15)) * 128 + ks * 64 + ((lane >> 4) * 16));
        bf16x8 bv = *(const bf16x8*)((const char*)vbuf + swz(av));
        zacc[dt] = MFMA16(pa, bv, zacc[dt]);
      }
    }
  }

  // z epilogue -> zb[b][s][h*64+d] (bf16)
#pragma unroll
  for (int dt = 0; dt < 4; ++dt)
#pragma unroll
    for (int r = 0; r < 4; ++r) {
      int srow = r0 + ((lane >> 4) << 2) + r;
      int dcol = dt * 16 + (lane & 15);
      zb[((size_t)b * SS + srow) * DD + h * 64 + dcol] = f2bf(zacc[dt][r]);
    }
}

// ---------------------------------------------------- K4: out = z @ wo + bo
__global__ __launch_bounds__(256) void out_gemm_kernel(
    const unsigned short* __restrict__ zb, const unsigned short* __restrict__ wot,
    const float* __restrict__ bo, float* __restrict__ outp) {
  __shared__ __align__(128) unsigned short As[128 * 64];
  __shared__ __align__(128) unsigned short Bs[128 * 64];
  const int tid = threadIdx.x, lane = tid & 63, w = tid >> 6;
  const int wr = (w >> 1) * 64, wc = (w & 1) * 64;
  const int m0 = blockIdx.x * 128;
  const int n0 = blockIdx.y * 128;

  f32x4 acc[4][4];
  f32x4 z4 = {0.f, 0.f, 0.f, 0.f};
#pragma unroll
  for (int i = 0; i < 4; ++i)
#pragma unroll
    for (int j = 0; j < 4; ++j) acc[i][j] = z4;

  for (int kt = 0; kt < 1024; kt += 64) {
    __syncthreads();
#pragma unroll
    for (int i = 0; i < 4; ++i) {
      unsigned obase = (unsigned)(w * 4096 + i * 1024);
      unsigned a = swz(obase + (unsigned)lane * 16);
      GLOAD16((const char*)zb + ((size_t)(m0 + (int)(a >> 7)) * 1024 + kt) * 2 + (a & 127),
              (char*)As + obase);
      GLOAD16((const char*)wot + ((size_t)(n0 + (int)(a >> 7)) * 1024 + kt) * 2 + (a & 127),
              (char*)Bs + obase);
    }
    __syncthreads();
#pragma unroll
    for (int ks = 0; ks < 2; ++ks) {
      bf16x8 af[4], bfr[4];
#pragma unroll
      for (int mi = 0; mi < 4; ++mi) {
        unsigned a = (unsigned)((wr + mi * 16 + (lane & 15)) * 128 + ks * 64 + ((lane >> 4) * 16));
        af[mi] = *(const bf16x8*)((const char*)As + swz(a));
      }
#pragma unroll
      for (int ni = 0; ni < 4; ++ni) {
        unsigned a = (unsigned)((wc + ni * 16 + (lane & 15)) * 128 + ks * 64 + ((lane >> 4) * 16));
        bfr[ni] = *(const bf16x8*)((const char*)Bs + swz(a));
      }
#pragma unroll
      for (int mi = 0; mi < 4; ++mi)
#pragma unroll
        for (int ni = 0; ni < 4; ++ni)
          acc[mi][ni] = MFMA16(af[mi], bfr[ni], acc[mi][ni]);
    }
  }
#pragma unroll
  for (int mi = 0; mi < 4; ++mi)
#pragma unroll
    for (int ni = 0; ni < 4; ++ni) {
      int col = n0 + wc + ni * 16 + (lane & 15);
      float bs = bo[col];
#pragma unroll
      for (int r = 0; r < 4; ++r) {
        int row = m0 + wr + mi * 16 + ((lane >> 4) << 2) + r;
        outp[(size_t)row * DD + col] = acc[mi][ni][r] + bs;
      }
    }
}

// ------------------------------------------------------------------ launcher
extern "C" void kernel_launch(void* const* d_in, const int* in_sizes, int n_in,
                              void* d_out, int out_size, void* d_ws, size_t ws_size,
                              hipStream_t stream) {
  const float* x    = (const float*)d_in[0];
  const float* mask = (const float*)d_in[1];
  const float* wq_w = (const float*)d_in[2];
  const float* wq_b = (const float*)d_in[3];
  const float* wk_w = (const float*)d_in[4];
  const float* wk_b = (const float*)d_in[5];
  const float* wv_w = (const float*)d_in[6];
  const float* wv_b = (const float*)d_in[7];
  const float* wo_w = (const float*)d_in[8];
  const float* wo_b = (const float*)d_in[9];

  float* outp = (float*)d_out;
  float* attn = outp + (size_t)8388608;
  float* qk   = attn + (size_t)134217728;
  float* qo   = qk + (size_t)134217728;
  float* ko   = qo + (size_t)8388608;
  float* vo   = ko + (size_t)8388608;

  char* ws = (char*)d_ws;
  unsigned short* xb  = (unsigned short*)(ws + 0);
  unsigned short* wqt = (unsigned short*)(ws + 16777216);
  unsigned short* wkt = (unsigned short*)(ws + 18874368);
  unsigned short* wvt = (unsigned short*)(ws + 20971520);
  unsigned short* wot = (unsigned short*)(ws + 23068672);
  unsigned short* qb  = (unsigned short*)(ws + 25165824);
  unsigned short* kb  = (unsigned short*)(ws + 41943040);
  unsigned short* vt  = (unsigned short*)(ws + 58720256);
  unsigned short* zb  = (unsigned short*)(ws + 75497472);

  cvt_x_kernel<<<8192, 256, 0, stream>>>(x, xb);
  transpose_w_kernel<<<dim3(32, 32, 4), dim3(32, 8), 0, stream>>>(
      wq_w, wk_w, wv_w, wo_w, wqt, wkt, wvt, wot);
  proj_gemm_kernel<<<dim3(64, 24), 256, 0, stream>>>(
      xb, wqt, wkt, wvt, wq_b, wk_b, wv_b, qo, ko, vo, qb, kb, vt);
  attn_kernel<<<dim3(16, 16, 8), 256, 0, stream>>>(qb, kb, vt, mask, qk, attn, zb);
  out_gemm_kernel<<<dim3(64, 8), 256, 0, stream>>>(zb, wot, wo_b, outp);
}